// Round 1
// baseline (770.836 us; speedup 1.0000x reference)
//
#include <hip/hip_runtime.h>

#define NB 32          // batch
#define NL 12          // layers
#define NH 12          // heads
#define NP 196         // patches (14x14)
#define GRID 14
#define SIDE 28
#define HW 784
#define AREA_THRESH 160

__global__ __launch_bounds__(256)
void maskgen_kernel(const float* __restrict__ att, int* __restrict__ out)
{
    const int b   = blockIdx.x;
    const int tid = threadIdx.x;

    __shared__ float  s_a[NP];
    __shared__ double s_red[256];
    __shared__ int    s_lab[HW];
    __shared__ int    s_cnt[HW];
    __shared__ int    s_scan[256];
    __shared__ int    s_flag;
    __shared__ int    s_best;
    __shared__ float  s_thr;

    // ---- Stage 1: per-patch mean over 12x12 (l,h); CLS row, keys 1..196.
    // Lane i reads att[l,b,h,0,1+i] -> wave-coalesced 196-float segments.
    if (tid < NP) {
        double acc = 0.0;
        #pragma unroll
        for (int l = 0; l < NL; ++l) {
            #pragma unroll
            for (int h = 0; h < NH; ++h) {
                size_t off = ((size_t)((l * NB + b) * NH + h)) * (size_t)(197 * 197)
                           + 1 + tid;
                acc += (double)att[off];
            }
        }
        s_a[tid] = (float)(acc * (1.0 / 144.0));
    }
    __syncthreads();

    // ---- Stage 2: threshold = mean of 784 upsampled pixels == mean of 196 patch means
    s_red[tid] = (tid < NP) ? (double)s_a[tid] : 0.0;
    __syncthreads();
    for (int s = 128; s > 0; s >>= 1) {
        if (tid < s) s_red[tid] += s_red[tid + s];
        __syncthreads();
    }
    if (tid == 0) s_thr = (float)(s_red[0] * (1.0 / 196.0));
    __syncthreads();
    const float thr = s_thr;

    // ---- Stage 3: init labels: mask ? flat index : HW (background sentinel)
    for (int p = tid; p < HW; p += 256) {
        int y = p / SIDE, x = p - y * SIDE;
        int patch = (y >> 1) * GRID + (x >> 1);
        s_lab[p] = (s_a[patch] > thr) ? p : HW;
    }
    __syncthreads();

    // ---- Stage 4: CCL min-label propagation (Gauss-Seidel + pointer shortcut).
    // Monotone decreasing, lower-bounded by component min -> same fixpoint as
    // the reference's 784 Jacobi iterations.
    for (;;) {
        if (tid == 0) s_flag = 0;
        __syncthreads();
        int ch = 0;
        for (int p = tid; p < HW; p += 256) {
            int l0 = s_lab[p];
            if (l0 == HW) continue;
            int y = p / SIDE, x = p - y * SIDE;
            int m = l0;
            if (y > 0)        m = min(m, s_lab[p - SIDE]);
            if (y < SIDE - 1) m = min(m, s_lab[p + SIDE]);
            if (x > 0)        m = min(m, s_lab[p - 1]);
            if (x < SIDE - 1) m = min(m, s_lab[p + 1]);
            m = min(m, s_lab[m]);          // shortcut: lab[m] <= m, same component
            if (m < l0) { s_lab[p] = m; ch = 1; }
        }
        if (ch) s_flag = 1;
        __syncthreads();
        int done = (s_flag == 0);
        __syncthreads();                   // protect read before next write of s_flag
        if (done) break;
    }

    // ---- Stage 5: bincount + argmax (ties -> smallest label, like np/jnp argmax)
    for (int p = tid; p < HW; p += 256) s_cnt[p] = 0;
    if (tid == 0) s_best = 0;
    __syncthreads();
    for (int p = tid; p < HW; p += 256) {
        int l0 = s_lab[p];
        if (l0 < HW) atomicAdd(&s_cnt[l0], 1);
    }
    __syncthreads();
    int lb = 0;
    for (int p = tid; p < HW; p += 256) {
        int key = (s_cnt[p] << 10) | (1023 - p);   // count<=784<1024, label<1024
        lb = max(lb, key);
    }
    atomicMax(&s_best, lb);
    __syncthreads();
    const int best     = s_best;
    const int max_area = best >> 10;
    const int max_lab  = 1023 - (best & 1023);
    const bool keep    = (max_area >= AREA_THRESH);

    // ---- Stage 6: final mask + stable partition (fg ascending, then bg ascending)
    int f0 = 0, f1 = 0, f2 = 0, f3 = 0, cnt = 0;
    if (tid < NP) {
        int p0 = tid * 4;
        int l;
        l = s_lab[p0 + 0]; f0 = keep ? (l == max_lab) : (l < HW);
        l = s_lab[p0 + 1]; f1 = keep ? (l == max_lab) : (l < HW);
        l = s_lab[p0 + 2]; f2 = keep ? (l == max_lab) : (l < HW);
        l = s_lab[p0 + 3]; f3 = keep ? (l == max_lab) : (l < HW);
        cnt = f0 + f1 + f2 + f3;
    }
    s_scan[tid] = cnt;
    __syncthreads();
    // Hillis-Steele inclusive scan over 256 chunk counts
    for (int d = 1; d < 256; d <<= 1) {
        int v   = s_scan[tid];
        int add = (tid >= d) ? s_scan[tid - d] : 0;
        __syncthreads();
        s_scan[tid] = v + add;
        __syncthreads();
    }
    const int nfg = s_scan[255];
    int e = (tid > 0) ? s_scan[tid - 1] : 0;   // exclusive prefix of fg before chunk
    if (tid < NP) {
        int p0 = tid * 4;
        int* ob = out + b * HW;
        int pos;
        pos = f0 ? e : (nfg + (p0 + 0 - e)); ob[pos] = p0 + 1; e += f0;
        pos = f1 ? e : (nfg + (p0 + 1 - e)); ob[pos] = p0 + 2; e += f1;
        pos = f2 ? e : (nfg + (p0 + 2 - e)); ob[pos] = p0 + 3; e += f2;
        pos = f3 ? e : (nfg + (p0 + 3 - e)); ob[pos] = p0 + 4; e += f3;
    }
}

extern "C" void kernel_launch(void* const* d_in, const int* in_sizes, int n_in,
                              void* d_out, int out_size, void* d_ws, size_t ws_size,
                              hipStream_t stream) {
    const float* att = (const float*)d_in[0];
    int* out = (int*)d_out;
    maskgen_kernel<<<NB, 256, 0, stream>>>(att, out);
}

// Round 2
// 763.876 us; speedup vs baseline: 1.0091x; 1.0091x over previous
//
#include <hip/hip_runtime.h>

#define NB 32          // batch
#define NL 12          // layers
#define NH 12          // heads
#define NP 196         // patches (14x14)
#define GRID 14
#define SIDE 28
#define HW 784
#define NSEG 144       // NL*NH rows of 196 floats each
#define ROWSTRIDE 38809  // 197*197

__global__ __launch_bounds__(256)
void maskgen_kernel(const float* __restrict__ att, int* __restrict__ out)
{
    const int b   = blockIdx.x;
    const int tid = threadIdx.x;
    const int w   = tid >> 6;   // wave 0..3
    const int j   = tid & 63;   // lane

    __shared__ double s_part[4][NP];   // per-wave column partial sums
    __shared__ float  s_a[NP];
    __shared__ double s_red[256];
    __shared__ int    s_plab[NP];      // patch-grid labels (sentinel NP = bg)
    __shared__ int    s_cnt[NP];
    __shared__ int    s_scan[256];
    __shared__ int    s_flag;
    __shared__ int    s_best;
    __shared__ float  s_thr;

    // ---- Stage 1: column sums of the 144 x 196 matrix (rows = (l,h) segs).
    // Wave w owns rows w, w+4, ... (36 rows); lanes cover 196 cols in 4 chunks.
    // All loads independent -> deep MLP instead of a serial miss chain.
    {
        double a0 = 0.0, a1 = 0.0, a2 = 0.0, a3 = 0.0;
        #pragma unroll
        for (int k = 0; k < 36; ++k) {
            int r = (k << 2) + w;              // row 0..143
            int l = r / NH, h = r - l * NH;
            const float* base = att
                + ((size_t)((l * NB + b) * NH + h)) * (size_t)ROWSTRIDE + 1;
            a0 += (double)base[j];
            a1 += (double)base[j + 64];
            a2 += (double)base[j + 128];
            if (j < 4) a3 += (double)base[j + 192];
        }
        s_part[w][j]       = a0;
        s_part[w][j + 64]  = a1;
        s_part[w][j + 128] = a2;
        if (j < 4) s_part[w][j + 192] = a3;
    }
    __syncthreads();
    if (tid < NP) {
        double t = s_part[0][tid] + s_part[1][tid] + s_part[2][tid] + s_part[3][tid];
        s_a[tid] = (float)(t * (1.0 / 144.0));
    }
    __syncthreads();

    // ---- Stage 2: threshold = mean of the 196 patch means
    s_red[tid] = (tid < NP) ? (double)s_a[tid] : 0.0;
    __syncthreads();
    for (int s = 128; s > 0; s >>= 1) {
        if (tid < s) s_red[tid] += s_red[tid + s];
        __syncthreads();
    }
    if (tid == 0) s_thr = (float)(s_red[0] * (1.0 / 196.0));
    __syncthreads();
    const float thr = s_thr;

    // ---- Stage 3: CCL on the 14x14 PATCH grid (mask constant on 2x2 blocks,
    // so patch-grid connectivity == pixel-grid connectivity; patch labels are
    // order-isomorphic to pixel labels, areas scale by exactly 4).
    const bool cell  = (tid < NP);
    const int  py    = cell ? tid / GRID : 0;
    const int  px    = cell ? tid - py * GRID : 0;
    if (cell) s_plab[tid] = (s_a[tid] > thr) ? tid : NP;
    __syncthreads();

    for (;;) {
        if (tid == 0) s_flag = 0;
        __syncthreads();
        int ch = 0;
        if (cell) {
            int l0 = s_plab[tid];
            if (l0 != NP) {
                int m = l0;
                if (py > 0)        m = min(m, s_plab[tid - GRID]);
                if (py < GRID - 1) m = min(m, s_plab[tid + GRID]);
                if (px > 0)        m = min(m, s_plab[tid - 1]);
                if (px < GRID - 1) m = min(m, s_plab[tid + 1]);
                m = min(m, s_plab[m]);     // pointer-shortcut (lab[m] <= m)
                if (m < l0) { s_plab[tid] = m; ch = 1; }
            }
        }
        if (ch) s_flag = 1;
        __syncthreads();
        int done = (s_flag == 0);
        __syncthreads();
        if (done) break;
    }

    // ---- Stage 4: component sizes + argmax (ties -> smallest label)
    if (cell) s_cnt[tid] = 0;
    if (tid == 0) s_best = 0;
    __syncthreads();
    if (cell) {
        int l0 = s_plab[tid];
        if (l0 < NP) atomicAdd(&s_cnt[l0], 1);
    }
    __syncthreads();
    if (cell) {
        int key = (s_cnt[tid] << 8) | (255 - tid);  // cnt<=196, lab<256
        atomicMax(&s_best, key);
    }
    __syncthreads();
    const int best      = s_best;
    const int max_pcnt  = best >> 8;
    const int max_plab  = 255 - (best & 255);
    const bool keep     = (max_pcnt * 4 >= 160);    // pixel area = 4 * patch count

    // ---- Stage 5: final mask + stable partition over 784 pixels
    int f0 = 0, f1 = 0, f2 = 0, f3 = 0, cnt = 0;
    if (tid < NP) {
        int p0 = tid * 4;
        #pragma unroll
        for (int q = 0; q < 4; ++q) {
            int p = p0 + q;
            int y = p / SIDE, x = p - y * SIDE;
            int patch = (y >> 1) * GRID + (x >> 1);
            int lv = s_plab[patch];
            int f = keep ? (lv == max_plab) : (lv < NP);
            if (q == 0) f0 = f; else if (q == 1) f1 = f;
            else if (q == 2) f2 = f; else f3 = f;
        }
        cnt = f0 + f1 + f2 + f3;
    }
    s_scan[tid] = cnt;
    __syncthreads();
    for (int d = 1; d < 256; d <<= 1) {
        int v   = s_scan[tid];
        int add = (tid >= d) ? s_scan[tid - d] : 0;
        __syncthreads();
        s_scan[tid] = v + add;
        __syncthreads();
    }
    const int nfg = s_scan[255];
    int e = (tid > 0) ? s_scan[tid - 1] : 0;
    if (tid < NP) {
        int p0 = tid * 4;
        int* ob = out + b * HW;
        int pos;
        pos = f0 ? e : (nfg + (p0 + 0 - e)); ob[pos] = p0 + 1; e += f0;
        pos = f1 ? e : (nfg + (p0 + 1 - e)); ob[pos] = p0 + 2; e += f1;
        pos = f2 ? e : (nfg + (p0 + 2 - e)); ob[pos] = p0 + 3; e += f2;
        pos = f3 ? e : (nfg + (p0 + 3 - e)); ob[pos] = p0 + 4; e += f3;
    }
}

extern "C" void kernel_launch(void* const* d_in, const int* in_sizes, int n_in,
                              void* d_out, int out_size, void* d_ws, size_t ws_size,
                              hipStream_t stream) {
    const float* att = (const float*)d_in[0];
    int* out = (int*)d_out;
    maskgen_kernel<<<NB, 256, 0, stream>>>(att, out);
}